// Round 1
// baseline (875.670 us; speedup 1.0000x reference)
//
#include <hip/hip_runtime.h>

#define NN 50000
#define NE 800000
#define D 128

typedef __attribute__((ext_vector_type(8))) short short8;
typedef __attribute__((ext_vector_type(4))) float f32x4;

#define SWZ(b) ((b) ^ ((((b)>>8)&7)<<4))

__device__ __forceinline__ unsigned int f2bf(float f){
  unsigned int u = __float_as_uint(f);
  return (u + 0x7FFFu + ((u>>16)&1u)) >> 16;   // RNE fp32 -> bf16 (finite inputs)
}

// ---------- CSR build ----------
__global__ void k_hist(const int* __restrict__ dst0, int* __restrict__ cnt){
  int e = blockIdx.x*256 + threadIdx.x;
  if(e < NE) atomicAdd(&cnt[dst0[e]], 1);
}

__global__ void k_scan(const int* __restrict__ cnt, int* __restrict__ rowptr){
  __shared__ int part[512];
  int t = threadIdx.x;
  const int C = (NN + 511)/512;
  int base = t*C;
  int s = 0;
  for(int i=0;i<C;i++){ int idx = base+i; if(idx<NN) s += cnt[idx]; }
  part[t] = s; __syncthreads();
  for(int off=1; off<512; off<<=1){
    int v = (t>=off) ? part[t-off] : 0;
    __syncthreads();
    part[t] += v;
    __syncthreads();
  }
  int run = (t==0) ? 0 : part[t-1];
  for(int i=0;i<C;i++){ int idx = base+i; if(idx<NN){ rowptr[idx] = run; run += cnt[idx]; } }
  if(t==511) rowptr[NN] = run;   // == NE
}

__global__ void k_dinv(int* __restrict__ cnt, float* __restrict__ dinv){
  int v = blockIdx.x*256+threadIdx.x;
  if(v<NN){ dinv[v] = rsqrtf((float)(cnt[v]+1)); cnt[v] = 0; }  // deg incl self-loop >= 1
}

__global__ void k_fill(const int* __restrict__ src0, const int* __restrict__ dst0,
                       const int* __restrict__ rowptr, int* __restrict__ cur,
                       int* __restrict__ csr_src){
  int e = blockIdx.x*256 + threadIdx.x;
  if(e<NE){
    int d = dst0[e];
    int pos = atomicAdd(&cur[d],1);
    csr_src[rowptr[d]+pos] = src0[e];
  }
}

__global__ void k_prep_w(const float* __restrict__ Wc2, unsigned short* __restrict__ wc2t){
  int id = blockIdx.x*256+threadIdx.x;
  if(id < 64*128){
    int c = id>>7, k = id&127;
    wc2t[id] = (unsigned short)f2bf(Wc2[k*64+c]);   // wc2t[col][k]
  }
}

// ---------- node-level GEMM: out = [bnrelu](in) @ W  [* dinv] [+ bias] ----------
// in [NN,128], W row-major stride 128, out [NN,128]
__global__ __launch_bounds__(256) void k_matmul(const float* __restrict__ in, const float* __restrict__ W,
    float* __restrict__ out, const float* __restrict__ ss, const float* __restrict__ dinv,
    const float* __restrict__ bias){
  __shared__ float At[128][68];   // transposed input tile, padded stride
  int t = threadIdx.x;
  int rb = blockIdx.x*64;
  {
    int row = t>>2; int gr = rb+row; int d0 = (t&3)*32;
    const float* src = in + (size_t)(gr < NN ? gr : NN-1)*D + d0;
    #pragma unroll
    for(int i=0;i<32;i+=4){
      float4 v = *(const float4*)(src+i);
      float vv[4]={v.x,v.y,v.z,v.w};
      #pragma unroll
      for(int j=0;j<4;j++){
        int d = d0+i+j; float x = vv[j];
        if(ss) x = fmaxf(fmaf(ss[d], x, ss[128+d]), 0.f);
        At[d][row] = x;
      }
    }
  }
  __syncthreads();
  int c0 = (t&31)*4, r0 = (t>>5)*8;
  float acc[8][4] = {};
  #pragma unroll 4
  for(int k=0;k<128;k++){
    float4 w = *(const float4*)(W + (size_t)k*D + c0);   // L2-hot
    float4 a0 = *(const float4*)(&At[k][r0]);            // LDS broadcast
    float4 a1 = *(const float4*)(&At[k][r0+4]);
    float ar[8]={a0.x,a0.y,a0.z,a0.w,a1.x,a1.y,a1.z,a1.w};
    float wr[4]={w.x,w.y,w.z,w.w};
    #pragma unroll
    for(int i=0;i<8;i++)
      #pragma unroll
      for(int j=0;j<4;j++)
        acc[i][j] = fmaf(ar[i], wr[j], acc[i][j]);
  }
  #pragma unroll
  for(int i=0;i<8;i++){
    int gr = rb + r0 + i;
    if(gr < NN){
      float sc = dinv ? dinv[gr] : 1.f;
      float4 o;
      o.x = acc[i][0]*sc; o.y = acc[i][1]*sc; o.z = acc[i][2]*sc; o.w = acc[i][3]*sc;
      if(bias){ o.x += bias[c0]; o.y += bias[c0+1]; o.z += bias[c0+2]; o.w += bias[c0+3]; }
      *(float4*)(out + (size_t)gr*D + c0) = o;
    }
  }
}

// ---------- gather: out[v] = dinv[v] * (U[v] + sum_{in-edges} U[src]) ----------
__global__ __launch_bounds__(128) void k_gather(const float* __restrict__ U, const int* __restrict__ rowptr,
    const int* __restrict__ csr_src, const float* __restrict__ dinv, float* __restrict__ out){
  int v = blockIdx.x; int d = threadIdx.x;
  int s = rowptr[v], e = rowptr[v+1];
  float acc = U[(size_t)v*D + d];
  for(int j=s;j<e;j++){
    acc += U[(size_t)csr_src[j]*D + d];
  }
  out[(size_t)v*D + d] = dinv[v]*acc;
}

// ---------- BN stats ----------
__global__ __launch_bounds__(256) void k_bnstats(const float* __restrict__ x, float* __restrict__ sums){
  __shared__ float l1[256], l2[256];
  int b = blockIdx.x, t = threadIdx.x;
  int ch = t&127, half = t>>7;
  int rend = min((b+1)*196, NN);
  float s=0.f, s2=0.f;
  for(int r = b*196+half; r < rend; r += 2){
    float v = x[(size_t)r*D + ch];
    s += v; s2 = fmaf(v,v,s2);
  }
  l1[t]=s; l2[t]=s2; __syncthreads();
  if(t<128){
    s = l1[t]+l1[t+128]; s2 = l2[t]+l2[t+128];
    atomicAdd(&sums[ch], s);
    atomicAdd(&sums[128+ch], s2);
  }
}

__global__ void k_bnfin(const float* __restrict__ sums, const float* __restrict__ g,
                        const float* __restrict__ be, float* __restrict__ ss){
  int c = threadIdx.x;
  if(c<128){
    float inv = 1.f/(float)NN;
    float mu = sums[c]*inv;
    float var = sums[128+c]*inv - mu*mu;
    float sc = g[c]*rsqrtf(var + 1e-5f);
    ss[c] = sc;
    ss[128+c] = fmaf(-sc, mu, be[c]);
  }
}

// ---------- edge head: z1 = relu(P[src]+Q[dst]); z2 = relu(z1@Wc2+bc2); out = z2@Wc3+bc3 ----------
__global__ __launch_bounds__(256) void k_edge(const int* __restrict__ src0, const int* __restrict__ dst0,
    const float* __restrict__ P, const float* __restrict__ Qm, const unsigned short* __restrict__ wc2t,
    const float* __restrict__ bc2, const float* __restrict__ wc3, const float* __restrict__ bc3,
    float* __restrict__ out){
  __shared__ uint4 sZ1v[64*16];   // z1 bf16 [64 edges][128], XOR-swizzled 16B granules
  __shared__ uint4 sWv[64*16];    // Wc2^T bf16 [64 cols][128 k], XOR-swizzled
  __shared__ float sWc3[128];
  __shared__ int sSrc[64], sDst[64];
  char* sZ1 = (char*)sZ1v;
  char* sW  = (char*)sWv;
  int t = threadIdx.x;
  int base = blockIdx.x*64;
  if(t<64) sSrc[t] = src0[base+t];
  else if(t<128) sDst[t-64] = dst0[base+t-64];
  if(t<128) sWc3[t] = wc3[t];
  {
    const uint4* gw = (const uint4*)wc2t;
    #pragma unroll
    for(int i=0;i<4;i++){
      int G = t*4+i;
      int byte = G*16;
      *(uint4*)(sW + SWZ(byte)) = gw[G];
    }
  }
  __syncthreads();
  {
    int r = t>>2; int d0 = (t&3)*32;
    const float* prow = P  + (size_t)sSrc[r]*D + d0;
    const float* qrow = Qm + (size_t)sDst[r]*D + d0;
    #pragma unroll
    for(int g=0; g<4; g++){
      float4 p0 = *(const float4*)(prow + g*8);
      float4 p1 = *(const float4*)(prow + g*8 + 4);
      float4 q0 = *(const float4*)(qrow + g*8);
      float4 q1 = *(const float4*)(qrow + g*8 + 4);
      float f0 = fmaxf(p0.x+q0.x, 0.f), f1 = fmaxf(p0.y+q0.y, 0.f);
      float f2 = fmaxf(p0.z+q0.z, 0.f), f3 = fmaxf(p0.w+q0.w, 0.f);
      float f4 = fmaxf(p1.x+q1.x, 0.f), f5 = fmaxf(p1.y+q1.y, 0.f);
      float f6 = fmaxf(p1.z+q1.z, 0.f), f7 = fmaxf(p1.w+q1.w, 0.f);
      uint4 pk;
      pk.x = f2bf(f0) | (f2bf(f1)<<16);
      pk.y = f2bf(f2) | (f2bf(f3)<<16);
      pk.z = f2bf(f4) | (f2bf(f5)<<16);
      pk.w = f2bf(f6) | (f2bf(f7)<<16);
      int byte = r*256 + ((t&3)*4 + g)*16;
      *(uint4*)(sZ1 + SWZ(byte)) = pk;
    }
  }
  __syncthreads();
  int w = t>>6, l = t&63;
  int lr = l&15, lk = l>>4;
  f32x4 acc[4] = {{0.f,0.f,0.f,0.f},{0.f,0.f,0.f,0.f},{0.f,0.f,0.f,0.f},{0.f,0.f,0.f,0.f}};
  #pragma unroll
  for(int kk=0; kk<4; kk++){
    int abyte = (16*w + lr)*256 + kk*64 + lk*16;
    short8 a = *(const short8*)(sZ1 + SWZ(abyte));
    #pragma unroll
    for(int n=0;n<4;n++){
      int bbyte = (16*n + lr)*256 + kk*64 + lk*16;
      short8 bf = *(const short8*)(sW + SWZ(bbyte));
      acc[n] = __builtin_amdgcn_mfma_f32_16x16x32_bf16(a, bf, acc[n], 0, 0, 0);
    }
  }
  float w30[4], w31[4], bb2[4];
  #pragma unroll
  for(int n=0;n<4;n++){
    int col = 16*n + lr;
    w30[n] = sWc3[col*2+0];
    w31[n] = sWc3[col*2+1];
    bb2[n] = bc2[col];
  }
  float c30 = bc3[0], c31 = bc3[1];
  #pragma unroll
  for(int reg=0; reg<4; reg++){
    float s0=0.f, s1=0.f;
    #pragma unroll
    for(int n=0;n<4;n++){
      float z = fmaxf(acc[n][reg] + bb2[n], 0.f);
      s0 = fmaf(z, w30[n], s0);
      s1 = fmaf(z, w31[n], s1);
    }
    #pragma unroll
    for(int off=1; off<16; off<<=1){
      s0 += __shfl_xor(s0, off, 64);
      s1 += __shfl_xor(s1, off, 64);
    }
    if(lr==0){
      int edge = base + 16*w + lk*4 + reg;
      float2 res; res.x = s0 + c30; res.y = s1 + c31;
      *(float2*)(out + (size_t)edge*2) = res;
    }
  }
}

extern "C" void kernel_launch(void* const* d_in, const int* in_sizes, int n_in,
                              void* d_out, int out_size, void* d_ws, size_t ws_size,
                              hipStream_t stream) {
  const float* x   = (const float*)d_in[0];
  const int* ei    = (const int*)d_in[1];
  const int* src0  = ei;
  const int* dst0  = ei + NE;
  const float* W1  = (const float*)d_in[2];
  const float* W2  = (const float*)d_in[4];
  const float* W3  = (const float*)d_in[6];
  const float* g1  = (const float*)d_in[8];
  const float* be1 = (const float*)d_in[9];
  const float* g2  = (const float*)d_in[10];
  const float* be2 = (const float*)d_in[11];
  const float* g3  = (const float*)d_in[12];
  const float* be3 = (const float*)d_in[13];
  const float* Wc1 = (const float*)d_in[14];
  const float* bc1 = (const float*)d_in[15];
  const float* Wc2 = (const float*)d_in[16];
  const float* bc2 = (const float*)d_in[17];
  const float* Wc3 = (const float*)d_in[18];
  const float* bc3 = (const float*)d_in[19];
  float* out = (float*)d_out;

  char* ws = (char*)d_ws;
  size_t off = 0;
  auto alloc = [&](size_t bytes) -> void* {
    void* p = ws + off;
    off += (bytes + 511) & ~(size_t)511;
    return p;
  };
  int*   rowptr  = (int*)alloc((NN+1)*sizeof(int));
  int*   cnt     = (int*)alloc(NN*sizeof(int));
  int*   csr_src = (int*)alloc(NE*sizeof(int));
  float* dinv    = (float*)alloc(NN*sizeof(float));
  float* U       = (float*)alloc((size_t)NN*D*sizeof(float));  // also reused as P
  float* OUT     = (float*)alloc((size_t)NN*D*sizeof(float));
  float* Qb      = (float*)alloc((size_t)NN*D*sizeof(float));
  float* sums    = (float*)alloc(256*sizeof(float));
  float* ss      = (float*)alloc(256*sizeof(float));
  unsigned short* wc2t = (unsigned short*)alloc(64*128*sizeof(unsigned short));

  // CSR by dst + degrees
  hipMemsetAsync(cnt, 0, NN*sizeof(int), stream);
  k_hist<<<NE/256, 256, 0, stream>>>(dst0, cnt);
  k_scan<<<1, 512, 0, stream>>>(cnt, rowptr);
  k_dinv<<<(NN+255)/256, 256, 0, stream>>>(cnt, dinv);
  k_fill<<<NE/256, 256, 0, stream>>>(src0, dst0, rowptr, cnt, csr_src);
  k_prep_w<<<32, 256, 0, stream>>>(Wc2, wc2t);

  const int MMB = (NN + 63)/64;   // 782

  // layer 1
  k_matmul<<<MMB, 256, 0, stream>>>(x, W1, U, nullptr, dinv, nullptr);
  k_gather<<<NN, 128, 0, stream>>>(U, rowptr, csr_src, dinv, OUT);
  hipMemsetAsync(sums, 0, 256*sizeof(float), stream);
  k_bnstats<<<256, 256, 0, stream>>>(OUT, sums);
  k_bnfin<<<1, 128, 0, stream>>>(sums, g1, be1, ss);
  // layer 2
  k_matmul<<<MMB, 256, 0, stream>>>(OUT, W2, U, ss, dinv, nullptr);
  k_gather<<<NN, 128, 0, stream>>>(U, rowptr, csr_src, dinv, OUT);
  hipMemsetAsync(sums, 0, 256*sizeof(float), stream);
  k_bnstats<<<256, 256, 0, stream>>>(OUT, sums);
  k_bnfin<<<1, 128, 0, stream>>>(sums, g2, be2, ss);
  // layer 3
  k_matmul<<<MMB, 256, 0, stream>>>(OUT, W3, U, ss, dinv, nullptr);
  k_gather<<<NN, 128, 0, stream>>>(U, rowptr, csr_src, dinv, OUT);
  hipMemsetAsync(sums, 0, 256*sizeof(float), stream);
  k_bnstats<<<256, 256, 0, stream>>>(OUT, sums);
  k_bnfin<<<1, 128, 0, stream>>>(sums, g3, be3, ss);

  // node projections for edge head: P = bnrelu(h3)@Wc1_top + bc1 ; Q = bnrelu(h3)@Wc1_bot
  k_matmul<<<MMB, 256, 0, stream>>>(OUT, Wc1, U, ss, nullptr, bc1);
  k_matmul<<<MMB, 256, 0, stream>>>(OUT, Wc1 + 128*128, Qb, ss, nullptr, nullptr);

  // edge MLP
  k_edge<<<NE/64, 256, 0, stream>>>(src0, dst0, U, Qb, wc2t, bc2, Wc3, bc3, out);
}

// Round 2
// 741.657 us; speedup vs baseline: 1.1807x; 1.1807x over previous
//
#include <hip/hip_runtime.h>

#define NN 50000
#define NE 800000
#define D 128

typedef __attribute__((ext_vector_type(8))) short short8;
typedef __attribute__((ext_vector_type(4))) float f32x4;

#define SWZ(b) ((b) ^ ((((b)>>8)&7)<<4))

__device__ __forceinline__ unsigned int f2bf(float f){
  unsigned int u = __float_as_uint(f);
  return (u + 0x7FFFu + ((u>>16)&1u)) >> 16;   // RNE fp32 -> bf16 (finite inputs)
}
__device__ __forceinline__ float bf2f(unsigned int u){
  return __uint_as_float(u<<16);
}

// ---------- CSR build ----------
__global__ void k_hist(const int* __restrict__ dst0, int* __restrict__ cnt){
  int e = blockIdx.x*256 + threadIdx.x;
  if(e < NE) atomicAdd(&cnt[dst0[e]], 1);
}

__global__ void k_scan(const int* __restrict__ cnt, int* __restrict__ rowptr){
  __shared__ int part[512];
  int t = threadIdx.x;
  const int C = (NN + 511)/512;
  int base = t*C;
  int s = 0;
  for(int i=0;i<C;i++){ int idx = base+i; if(idx<NN) s += cnt[idx]; }
  part[t] = s; __syncthreads();
  for(int off=1; off<512; off<<=1){
    int v = (t>=off) ? part[t-off] : 0;
    __syncthreads();
    part[t] += v;
    __syncthreads();
  }
  int run = (t==0) ? 0 : part[t-1];
  for(int i=0;i<C;i++){ int idx = base+i; if(idx<NN){ rowptr[idx] = run; run += cnt[idx]; } }
  if(t==511) rowptr[NN] = run;   // == NE
}

__global__ void k_dinv(int* __restrict__ cnt, float* __restrict__ dinv){
  int v = blockIdx.x*256+threadIdx.x;
  if(v<NN){ dinv[v] = rsqrtf((float)(cnt[v]+1)); cnt[v] = 0; }  // deg incl self-loop >= 1
}

__global__ void k_fill(const int* __restrict__ src0, const int* __restrict__ dst0,
                       const int* __restrict__ rowptr, int* __restrict__ cur,
                       int* __restrict__ csr_src, int* __restrict__ csr_dst,
                       int* __restrict__ csr_eid){
  int e = blockIdx.x*256 + threadIdx.x;
  if(e<NE){
    int d = dst0[e];
    int pos = atomicAdd(&cur[d],1);
    int slot = rowptr[d]+pos;
    csr_src[slot] = src0[e];
    csr_dst[slot] = d;
    csr_eid[slot] = e;
  }
}

// wT[c*128+k] = bf16(W[k*Ncols + c]); total = Ncols*128
__global__ void k_prepw(const float* __restrict__ W, unsigned short* __restrict__ wT,
                        int Ncols, int total){
  int id = blockIdx.x*256+threadIdx.x;
  if(id < total){
    int c = id>>7, k = id&127;
    wT[(size_t)c*128+k] = (unsigned short)f2bf(W[(size_t)k*Ncols+c]);
  }
}

// fp32 x -> bf16 X16, 8 elems/thread
__global__ void k_cvt(const float* __restrict__ x, unsigned short* __restrict__ X16){
  int id = blockIdx.x*256 + threadIdx.x;
  if(id < NN*D/8){
    const float4* s = (const float4*)(x + (size_t)id*8);
    float4 a = s[0], b = s[1];
    uint4 o;
    o.x = f2bf(a.x) | (f2bf(a.y)<<16);
    o.y = f2bf(a.z) | (f2bf(a.w)<<16);
    o.z = f2bf(b.x) | (f2bf(b.y)<<16);
    o.w = f2bf(b.z) | (f2bf(b.w)<<16);
    *(uint4*)(X16 + (size_t)id*8) = o;
  }
}

// ---------- node GEMM (bf16 MFMA): out = [bnrelu](in) @ W  [*dinv] [+bias] ----------
// in bf16 [NN][128]; wT bf16 [128 col][128 k]; out bf16 [NN][128]
__global__ __launch_bounds__(256) void k_mm(const unsigned short* __restrict__ in,
    const unsigned short* __restrict__ wT, unsigned short* __restrict__ outp,
    const float* __restrict__ ss, const float* __restrict__ dinv,
    const float* __restrict__ bias){
  __shared__ char sA[64*256];   // bf16 [64 rows][128], XOR-swizzled
  int t = threadIdx.x;
  int rb = blockIdx.x*64;
  {
    int row = t>>2, ch = t&3;
    int gr = rb+row; if(gr >= NN) gr = NN-1;
    const uint4* src = (const uint4*)(in + (size_t)gr*D + ch*32);
    #pragma unroll
    for(int i=0;i<4;i++){
      uint4 v = src[i];
      if(ss){
        int d = ch*32 + i*8;
        unsigned int* pv = (unsigned int*)&v;
        #pragma unroll
        for(int j=0;j<4;j++){
          unsigned int u = pv[j];
          int dd = d + j*2;
          float lo = bf2f(u & 0xFFFFu);
          float hi = __uint_as_float(u & 0xFFFF0000u);
          lo = fmaxf(fmaf(ss[dd],   lo, ss[128+dd]),   0.f);
          hi = fmaxf(fmaf(ss[dd+1], hi, ss[128+dd+1]), 0.f);
          pv[j] = f2bf(lo) | (f2bf(hi)<<16);
        }
      }
      int byte = row*256 + ch*64 + i*16;
      *(uint4*)(sA + SWZ(byte)) = v;
    }
  }
  __syncthreads();
  int w = t>>6, l = t&63, lr = l&15, lk = l>>4;
  f32x4 acc[8] = {};
  #pragma unroll
  for(int kk=0; kk<4; kk++){
    int abyte = (16*w + lr)*256 + kk*64 + lk*16;
    short8 a = *(const short8*)(sA + SWZ(abyte));
    #pragma unroll
    for(int n=0;n<8;n++){
      short8 b = *(const short8*)(wT + (size_t)(16*n+lr)*128 + kk*32 + lk*8);
      acc[n] = __builtin_amdgcn_mfma_f32_16x16x32_bf16(a, b, acc[n], 0, 0, 0);
    }
  }
  __syncthreads();   // reuse sA as bf16 output staging
  {
    float dv[4];
    #pragma unroll
    for(int reg=0;reg<4;reg++){
      int gr = rb + w*16 + lk*4 + reg;
      dv[reg] = dinv ? dinv[gr<NN?gr:NN-1] : 1.f;
    }
    #pragma unroll
    for(int n=0;n<8;n++){
      float bs = bias ? bias[16*n+lr] : 0.f;
      #pragma unroll
      for(int reg=0;reg<4;reg++){
        float v = fmaf(acc[n][reg], dv[reg], bs);
        int byte = ((w*16 + lk*4 + reg)*128 + 16*n + lr)*2;
        *(unsigned short*)(sA + SWZ(byte)) = (unsigned short)f2bf(v);
      }
    }
  }
  __syncthreads();
  {
    int row = t>>2, ch = t&3;
    int gr = rb+row;
    if(gr < NN){
      uint4* dstp = (uint4*)(outp + (size_t)gr*D + ch*32);
      #pragma unroll
      for(int i=0;i<4;i++){
        int byte = row*256 + ch*64 + i*16;
        dstp[i] = *(const uint4*)(sA + SWZ(byte));
      }
    }
  }
}

// ---------- gather: out[v] = bf16(dinv[v] * (U[v] + sum_in U[src])) ----------
__global__ __launch_bounds__(128) void k_gather16(const unsigned short* __restrict__ U,
    const int* __restrict__ rowptr, const int* __restrict__ csr_src,
    const float* __restrict__ dinv, unsigned short* __restrict__ outp){
  int v = blockIdx.x; int d = threadIdx.x;
  int s = rowptr[v], e = rowptr[v+1];
  float acc = bf2f(U[(size_t)v*D + d]);
  for(int j=s;j<e;j++){
    acc += bf2f(U[(size_t)csr_src[j]*D + d]);
  }
  outp[(size_t)v*D + d] = (unsigned short)f2bf(dinv[v]*acc);
}

// ---------- BN stats (bf16 input) ----------
__global__ __launch_bounds__(256) void k_bnstats16(const unsigned short* __restrict__ x,
    float* __restrict__ sums){
  __shared__ float l1[256], l2[256];
  int b = blockIdx.x, t = threadIdx.x;
  int ch = t&127, half = t>>7;
  int rend = min((b+1)*196, NN);
  float s=0.f, s2=0.f;
  for(int r = b*196+half; r < rend; r += 2){
    float v = bf2f(x[(size_t)r*D + ch]);
    s += v; s2 = fmaf(v,v,s2);
  }
  l1[t]=s; l2[t]=s2; __syncthreads();
  if(t<128){
    s = l1[t]+l1[t+128]; s2 = l2[t]+l2[t+128];
    atomicAdd(&sums[ch], s);
    atomicAdd(&sums[128+ch], s2);
  }
}

__global__ void k_bnfin(const float* __restrict__ sums, const float* __restrict__ g,
                        const float* __restrict__ be, float* __restrict__ ss){
  int c = threadIdx.x;
  if(c<128){
    float inv = 1.f/(float)NN;
    float mu = sums[c]*inv;
    float var = sums[128+c]*inv - mu*mu;
    float sc = g[c]*rsqrtf(var + 1e-5f);
    ss[c] = sc;
    ss[128+c] = fmaf(-sc, mu, be[c]);
  }
}

// ---------- edge head over dst-CSR-ordered edges ----------
__global__ __launch_bounds__(256) void k_edge(const int* __restrict__ csr_src,
    const int* __restrict__ csr_dst, const int* __restrict__ csr_eid,
    const unsigned short* __restrict__ P16, const unsigned short* __restrict__ Q16,
    const unsigned short* __restrict__ wc2t, const float* __restrict__ bc2,
    const float* __restrict__ wc3, const float* __restrict__ bc3,
    float* __restrict__ out){
  __shared__ char sZ1[64*256];    // z1 bf16 [64 edges][128], swizzled
  __shared__ char sW[64*256];     // Wc2^T bf16 [64 cols][128 k], swizzled
  __shared__ float sWc3[128];
  __shared__ int sSrc[64], sDst[64], sEid[64];
  int t = threadIdx.x;
  int base = blockIdx.x*64;
  if(t<64) sSrc[t] = csr_src[base+t];
  else if(t<128) sDst[t-64] = csr_dst[base+t-64];
  else if(t<192) sEid[t-128] = csr_eid[base+t-128];
  if(t<128) sWc3[t] = wc3[t];
  {
    const uint4* gw = (const uint4*)wc2t;
    #pragma unroll
    for(int i=0;i<4;i++){
      int G = t*4+i;
      int byte = G*16;
      *(uint4*)(sW + SWZ(byte)) = gw[G];
    }
  }
  __syncthreads();
  {
    int r = t>>2, ch = t&3;
    const uint4* prow = (const uint4*)(P16 + (size_t)sSrc[r]*D + ch*32);
    const uint4* qrow = (const uint4*)(Q16 + (size_t)sDst[r]*D + ch*32);
    #pragma unroll
    for(int g=0; g<4; g++){
      uint4 pv = prow[g], qv = qrow[g];
      unsigned int* pp=(unsigned int*)&pv;
      unsigned int* qq=(unsigned int*)&qv;
      uint4 ov; unsigned int* oo=(unsigned int*)&ov;
      #pragma unroll
      for(int j=0;j<4;j++){
        float plo = bf2f(pp[j] & 0xFFFFu);
        float phi = __uint_as_float(pp[j] & 0xFFFF0000u);
        float qlo = bf2f(qq[j] & 0xFFFFu);
        float qhi = __uint_as_float(qq[j] & 0xFFFF0000u);
        float lo = fmaxf(plo+qlo, 0.f);
        float hi = fmaxf(phi+qhi, 0.f);
        oo[j] = f2bf(lo) | (f2bf(hi)<<16);
      }
      int byte = r*256 + ch*64 + g*16;
      *(uint4*)(sZ1 + SWZ(byte)) = ov;
    }
  }
  __syncthreads();
  int w = t>>6, l = t&63;
  int lr = l&15, lk = l>>4;
  f32x4 acc[4] = {{0.f,0.f,0.f,0.f},{0.f,0.f,0.f,0.f},{0.f,0.f,0.f,0.f},{0.f,0.f,0.f,0.f}};
  #pragma unroll
  for(int kk=0; kk<4; kk++){
    int abyte = (16*w + lr)*256 + kk*64 + lk*16;
    short8 a = *(const short8*)(sZ1 + SWZ(abyte));
    #pragma unroll
    for(int n=0;n<4;n++){
      int bbyte = (16*n + lr)*256 + kk*64 + lk*16;
      short8 bf = *(const short8*)(sW + SWZ(bbyte));
      acc[n] = __builtin_amdgcn_mfma_f32_16x16x32_bf16(a, bf, acc[n], 0, 0, 0);
    }
  }
  float w30[4], w31[4], bb2[4];
  #pragma unroll
  for(int n=0;n<4;n++){
    int col = 16*n + lr;
    w30[n] = sWc3[col*2+0];
    w31[n] = sWc3[col*2+1];
    bb2[n] = bc2[col];
  }
  float c30 = bc3[0], c31 = bc3[1];
  #pragma unroll
  for(int reg=0; reg<4; reg++){
    float s0=0.f, s1=0.f;
    #pragma unroll
    for(int n=0;n<4;n++){
      float z = fmaxf(acc[n][reg] + bb2[n], 0.f);
      s0 = fmaf(z, w30[n], s0);
      s1 = fmaf(z, w31[n], s1);
    }
    #pragma unroll
    for(int off=1; off<16; off<<=1){
      s0 += __shfl_xor(s0, off, 64);
      s1 += __shfl_xor(s1, off, 64);
    }
    if(lr==0){
      int eid = sEid[16*w + lk*4 + reg];
      float2 res; res.x = s0 + c30; res.y = s1 + c31;
      *(float2*)(out + (size_t)eid*2) = res;
    }
  }
}

extern "C" void kernel_launch(void* const* d_in, const int* in_sizes, int n_in,
                              void* d_out, int out_size, void* d_ws, size_t ws_size,
                              hipStream_t stream) {
  const float* x   = (const float*)d_in[0];
  const int* ei    = (const int*)d_in[1];
  const int* src0  = ei;
  const int* dst0  = ei + NE;
  const float* W1  = (const float*)d_in[2];
  const float* W2  = (const float*)d_in[4];
  const float* W3  = (const float*)d_in[6];
  const float* g1  = (const float*)d_in[8];
  const float* be1 = (const float*)d_in[9];
  const float* g2  = (const float*)d_in[10];
  const float* be2 = (const float*)d_in[11];
  const float* g3  = (const float*)d_in[12];
  const float* be3 = (const float*)d_in[13];
  const float* Wc1 = (const float*)d_in[14];
  const float* bc1 = (const float*)d_in[15];
  const float* Wc2 = (const float*)d_in[16];
  const float* bc2 = (const float*)d_in[17];
  const float* Wc3 = (const float*)d_in[18];
  const float* bc3 = (const float*)d_in[19];
  float* out = (float*)d_out;

  char* ws = (char*)d_ws;
  size_t off = 0;
  auto alloc = [&](size_t bytes) -> void* {
    void* p = ws + off;
    off += (bytes + 511) & ~(size_t)511;
    return p;
  };
  int*   rowptr  = (int*)alloc((NN+1)*sizeof(int));
  int*   cnt     = (int*)alloc(NN*sizeof(int));
  int*   csr_src = (int*)alloc(NE*sizeof(int));
  int*   csr_dst = (int*)alloc(NE*sizeof(int));
  int*   csr_eid = (int*)alloc(NE*sizeof(int));
  float* dinv    = (float*)alloc(NN*sizeof(float));
  unsigned short* X16 = (unsigned short*)alloc((size_t)NN*D*2);
  unsigned short* U16 = (unsigned short*)alloc((size_t)NN*D*2);  // also P
  unsigned short* H16 = (unsigned short*)alloc((size_t)NN*D*2);
  unsigned short* Q16 = (unsigned short*)alloc((size_t)NN*D*2);
  float* sums    = (float*)alloc(256*sizeof(float));
  float* ss      = (float*)alloc(256*sizeof(float));
  unsigned short* w1T  = (unsigned short*)alloc(128*128*2);
  unsigned short* w2T  = (unsigned short*)alloc(128*128*2);
  unsigned short* w3T  = (unsigned short*)alloc(128*128*2);
  unsigned short* wc1aT= (unsigned short*)alloc(128*128*2);
  unsigned short* wc1bT= (unsigned short*)alloc(128*128*2);
  unsigned short* wc2T = (unsigned short*)alloc(64*128*2);

  // CSR by dst + degrees
  hipMemsetAsync(cnt, 0, NN*sizeof(int), stream);
  k_hist<<<NE/256, 256, 0, stream>>>(dst0, cnt);
  k_scan<<<1, 512, 0, stream>>>(cnt, rowptr);
  k_dinv<<<(NN+255)/256, 256, 0, stream>>>(cnt, dinv);
  k_fill<<<NE/256, 256, 0, stream>>>(src0, dst0, rowptr, cnt, csr_src, csr_dst, csr_eid);

  // weight preps + input cvt
  k_prepw<<<64, 256, 0, stream>>>(W1, w1T, 128, 128*128);
  k_prepw<<<64, 256, 0, stream>>>(W2, w2T, 128, 128*128);
  k_prepw<<<64, 256, 0, stream>>>(W3, w3T, 128, 128*128);
  k_prepw<<<64, 256, 0, stream>>>(Wc1, wc1aT, 128, 128*128);
  k_prepw<<<64, 256, 0, stream>>>(Wc1 + 128*128, wc1bT, 128, 128*128);
  k_prepw<<<32, 256, 0, stream>>>(Wc2, wc2T, 64, 64*128);
  k_cvt<<<(NN*D/8 + 255)/256, 256, 0, stream>>>(x, X16);

  const int MMB = (NN + 63)/64;   // 782

  // layer 1
  k_mm<<<MMB, 256, 0, stream>>>(X16, w1T, U16, nullptr, dinv, nullptr);
  k_gather16<<<NN, 128, 0, stream>>>(U16, rowptr, csr_src, dinv, H16);
  hipMemsetAsync(sums, 0, 256*sizeof(float), stream);
  k_bnstats16<<<256, 256, 0, stream>>>(H16, sums);
  k_bnfin<<<1, 128, 0, stream>>>(sums, g1, be1, ss);
  // layer 2
  k_mm<<<MMB, 256, 0, stream>>>(H16, w2T, U16, ss, dinv, nullptr);
  k_gather16<<<NN, 128, 0, stream>>>(U16, rowptr, csr_src, dinv, H16);
  hipMemsetAsync(sums, 0, 256*sizeof(float), stream);
  k_bnstats16<<<256, 256, 0, stream>>>(H16, sums);
  k_bnfin<<<1, 128, 0, stream>>>(sums, g2, be2, ss);
  // layer 3
  k_mm<<<MMB, 256, 0, stream>>>(H16, w3T, U16, ss, dinv, nullptr);
  k_gather16<<<NN, 128, 0, stream>>>(U16, rowptr, csr_src, dinv, H16);
  hipMemsetAsync(sums, 0, 256*sizeof(float), stream);
  k_bnstats16<<<256, 256, 0, stream>>>(H16, sums);
  k_bnfin<<<1, 128, 0, stream>>>(sums, g3, be3, ss);

  // head projections: P = bnrelu(H)@Wc1_top + bc1 ; Q = bnrelu(H)@Wc1_bot
  k_mm<<<MMB, 256, 0, stream>>>(H16, wc1aT, U16, ss, nullptr, bc1);
  k_mm<<<MMB, 256, 0, stream>>>(H16, wc1bT, Q16, ss, nullptr, nullptr);

  // edge MLP over CSR-ordered edges
  k_edge<<<NE/64, 256, 0, stream>>>(csr_src, csr_dst, csr_eid, U16, Q16, wc2T,
                                    bc2, Wc3, bc3, out);
}

// Round 3
// 546.933 us; speedup vs baseline: 1.6011x; 1.3560x over previous
//
#include <hip/hip_runtime.h>

#define NN 50000
#define NE 800000
#define D 128

typedef __attribute__((ext_vector_type(8))) short short8;
typedef __attribute__((ext_vector_type(4))) float f32x4;

#define SWZ(b) ((b) ^ ((((b)>>8)&7)<<4))

__device__ __forceinline__ unsigned int f2bf(float f){
  unsigned int u = __float_as_uint(f);
  return (u + 0x7FFFu + ((u>>16)&1u)) >> 16;   // RNE fp32 -> bf16 (finite inputs)
}
__device__ __forceinline__ float bf2f(unsigned int u){
  return __uint_as_float(u<<16);
}

// ---------- CSR build ----------
__global__ void k_hist(const int* __restrict__ dst0, int* __restrict__ cnt){
  int e = blockIdx.x*256 + threadIdx.x;
  if(e < NE) atomicAdd(&cnt[dst0[e]], 1);
}

// per-block sums of cnt (196 blocks x 256)
__global__ __launch_bounds__(256) void k_scanA(const int* __restrict__ cnt, int* __restrict__ bsum){
  __shared__ int sh[256];
  int b = blockIdx.x, t = threadIdx.x;
  int i = b*256 + t;
  int v = (i<NN) ? cnt[i] : 0;
  sh[t] = v; __syncthreads();
  for(int off=128; off>0; off>>=1){
    if(t<off) sh[t] += sh[t+off];
    __syncthreads();
  }
  if(t==0) bsum[b] = sh[0];
}

// exclusive scan of NB block sums (1 block)
__global__ __launch_bounds__(256) void k_scanB(const int* __restrict__ bsum, int* __restrict__ boff, int NB){
  __shared__ int sh[256];
  int t = threadIdx.x;
  int v = (t<NB) ? bsum[t] : 0;
  sh[t] = v; __syncthreads();
  for(int off=1; off<256; off<<=1){
    int add = (t>=off) ? sh[t-off] : 0;
    __syncthreads();
    sh[t] += add;
    __syncthreads();
  }
  if(t<NB) boff[t] = sh[t] - v;   // exclusive
}

// local exclusive scan + base offset -> rowptr; also dinv and cnt reset
__global__ __launch_bounds__(256) void k_scanC(const int* __restrict__ cnt, const int* __restrict__ boff,
    int* __restrict__ rowptr, float* __restrict__ dinv, int* __restrict__ cntz){
  __shared__ int sh[256];
  int b = blockIdx.x, t = threadIdx.x;
  int i = b*256 + t;
  int v = (i<NN) ? cnt[i] : 0;
  sh[t] = v; __syncthreads();
  for(int off=1; off<256; off<<=1){
    int add = (t>=off) ? sh[t-off] : 0;
    __syncthreads();
    sh[t] += add;
    __syncthreads();
  }
  int excl = sh[t] - v;
  if(i<NN){
    rowptr[i] = boff[b] + excl;
    dinv[i] = rsqrtf((float)(v+1));   // deg incl self-loop
    cntz[i] = 0;
  }
  if(b==gridDim.x-1 && t==255) rowptr[NN] = NE;
}

__global__ void k_fill(const int* __restrict__ src0, const int* __restrict__ dst0,
                       const int* __restrict__ rowptr, int* __restrict__ cur,
                       int* __restrict__ csr_src, int* __restrict__ csr_dst,
                       int* __restrict__ csr_eid){
  int e = blockIdx.x*256 + threadIdx.x;
  if(e<NE){
    int d = dst0[e];
    int pos = atomicAdd(&cur[d],1);
    int slot = rowptr[d]+pos;
    csr_src[slot] = src0[e];
    csr_dst[slot] = d;
    csr_eid[slot] = e;
  }
}

// all weight transposes+bf16 in one kernel.
// segments: 5 x 16384 (W1,W2,W3,Wc1a,Wc1b) + 8192 (Wc2)
__global__ void k_prep_all(const float* __restrict__ W1, const float* __restrict__ W2,
    const float* __restrict__ W3, const float* __restrict__ Wc1, const float* __restrict__ Wc2,
    unsigned short* __restrict__ w1T, unsigned short* __restrict__ w2T,
    unsigned short* __restrict__ w3T, unsigned short* __restrict__ wc1aT,
    unsigned short* __restrict__ wc1bT, unsigned short* __restrict__ wc2T){
  int id = blockIdx.x*256 + threadIdx.x;
  if(id < 81920){
    int seg = id >> 14, q = id & 16383;
    int c = q>>7, k = q&127;
    const float* W; unsigned short* wT;
    switch(seg){
      case 0: W=W1; wT=w1T; break;
      case 1: W=W2; wT=w2T; break;
      case 2: W=W3; wT=w3T; break;
      case 3: W=Wc1; wT=wc1aT; break;
      default: W=Wc1+128*128; wT=wc1bT; break;
    }
    wT[q] = (unsigned short)f2bf(W[(size_t)k*128+c]);
  } else if(id < 90112){
    int q = id - 81920;
    int c = q>>7, k = q&127;
    wc2T[q] = (unsigned short)f2bf(Wc2[(size_t)k*64+c]);
  }
}

// ---------- node GEMM (bf16 MFMA): out = [bnrelu](in) @ W  [*dinv] [+bias] ----------
// in bf16 [NN][128] (or fp32 via in32); wT bf16 [col][k]; out bf16 [NN][128]
__global__ __launch_bounds__(256) void k_mm(const unsigned short* __restrict__ in,
    const float* __restrict__ in32,
    const unsigned short* __restrict__ wT, unsigned short* __restrict__ outp,
    const float* __restrict__ ss, const float* __restrict__ dinv,
    const float* __restrict__ bias){
  __shared__ char sA[64*256];   // bf16 [64 rows][128], XOR-swizzled
  int t = threadIdx.x;
  int rb = blockIdx.x*64;
  {
    int row = t>>2, ch = t&3;
    int gr = rb+row; if(gr >= NN) gr = NN-1;
    if(in32){
      const float4* src = (const float4*)(in32 + (size_t)gr*D + ch*32);
      #pragma unroll
      for(int i=0;i<4;i++){
        float4 a = src[2*i], b = src[2*i+1];
        uint4 v;
        v.x = f2bf(a.x) | (f2bf(a.y)<<16);
        v.y = f2bf(a.z) | (f2bf(a.w)<<16);
        v.z = f2bf(b.x) | (f2bf(b.y)<<16);
        v.w = f2bf(b.z) | (f2bf(b.w)<<16);
        int byte = row*256 + ch*64 + i*16;
        *(uint4*)(sA + SWZ(byte)) = v;
      }
    } else {
      const uint4* src = (const uint4*)(in + (size_t)gr*D + ch*32);
      #pragma unroll
      for(int i=0;i<4;i++){
        uint4 v = src[i];
        if(ss){
          int d = ch*32 + i*8;
          unsigned int* pv = (unsigned int*)&v;
          #pragma unroll
          for(int j=0;j<4;j++){
            unsigned int u = pv[j];
            int dd = d + j*2;
            float lo = bf2f(u & 0xFFFFu);
            float hi = __uint_as_float(u & 0xFFFF0000u);
            lo = fmaxf(fmaf(ss[dd],   lo, ss[128+dd]),   0.f);
            hi = fmaxf(fmaf(ss[dd+1], hi, ss[128+dd+1]), 0.f);
            pv[j] = f2bf(lo) | (f2bf(hi)<<16);
          }
        }
        int byte = row*256 + ch*64 + i*16;
        *(uint4*)(sA + SWZ(byte)) = v;
      }
    }
  }
  __syncthreads();
  int w = t>>6, l = t&63, lr = l&15, lk = l>>4;
  f32x4 acc[8] = {};
  #pragma unroll
  for(int kk=0; kk<4; kk++){
    int abyte = (16*w + lr)*256 + kk*64 + lk*16;
    short8 a = *(const short8*)(sA + SWZ(abyte));
    #pragma unroll
    for(int n=0;n<8;n++){
      short8 b = *(const short8*)(wT + (size_t)(16*n+lr)*128 + kk*32 + lk*8);
      acc[n] = __builtin_amdgcn_mfma_f32_16x16x32_bf16(a, b, acc[n], 0, 0, 0);
    }
  }
  __syncthreads();   // reuse sA as bf16 output staging
  {
    float dv[4];
    #pragma unroll
    for(int reg=0;reg<4;reg++){
      int gr = rb + w*16 + lk*4 + reg;
      dv[reg] = dinv ? dinv[gr<NN?gr:NN-1] : 1.f;
    }
    #pragma unroll
    for(int n=0;n<8;n++){
      float bs = bias ? bias[16*n+lr] : 0.f;
      #pragma unroll
      for(int reg=0;reg<4;reg++){
        float v = fmaf(acc[n][reg], dv[reg], bs);
        int byte = ((w*16 + lk*4 + reg)*128 + 16*n + lr)*2;
        *(unsigned short*)(sA + SWZ(byte)) = (unsigned short)f2bf(v);
      }
    }
  }
  __syncthreads();
  {
    int row = t>>2, ch = t&3;
    int gr = rb+row;
    if(gr < NN){
      uint4* dstp = (uint4*)(outp + (size_t)gr*D + ch*32);
      #pragma unroll
      for(int i=0;i<4;i++){
        int byte = row*256 + ch*64 + i*16;
        dstp[i] = *(const uint4*)(sA + SWZ(byte));
      }
    }
  }
}

// ---------- gather: out[v] = bf16(dinv[v] * (U[v] + sum_in U[src])) ----------
// one wave per node; lane handles 2 channels via uint loads
__global__ __launch_bounds__(256) void k_gather16(const unsigned short* __restrict__ U,
    const int* __restrict__ rowptr, const int* __restrict__ csr_src,
    const float* __restrict__ dinv, unsigned short* __restrict__ outp){
  int node = blockIdx.x*4 + (threadIdx.x>>6);
  int l = threadIdx.x&63;
  if(node >= NN) return;
  const unsigned* U32 = (const unsigned*)U;
  unsigned u = U32[(size_t)node*64 + l];
  float a0 = bf2f(u & 0xFFFFu);
  float a1 = __uint_as_float(u & 0xFFFF0000u);
  int s = rowptr[node], e = rowptr[node+1];
  for(int base=s; base<e; base+=64){
    int idx = (base+l < e) ? csr_src[base+l] : 0;
    int n = min(64, e-base);
    for(int k=0;k<n;k++){
      int src = __shfl(idx, k, 64);
      unsigned v = U32[(size_t)src*64 + l];
      a0 += bf2f(v & 0xFFFFu);
      a1 += __uint_as_float(v & 0xFFFF0000u);
    }
  }
  float dv = dinv[node];
  ((unsigned*)outp)[(size_t)node*64 + l] = f2bf(a0*dv) | (f2bf(a1*dv)<<16);
}

// ---------- BN stats (bf16 input, uint loads) ----------
__global__ __launch_bounds__(256) void k_bnstats16(const unsigned short* __restrict__ x,
    float* __restrict__ sums){
  __shared__ float l0[256], l1[256], l2[256], l3[256];
  int b = blockIdx.x, t = threadIdx.x;
  int cp = t&63, rg = t>>6;
  const unsigned* x32 = (const unsigned*)x;
  int rend = min((b+1)*196, NN);
  float s0=0.f,s1=0.f,q0=0.f,q1=0.f;
  for(int r = b*196+rg; r < rend; r += 4){
    unsigned u = x32[(size_t)r*64 + cp];
    float lo = bf2f(u & 0xFFFFu);
    float hi = __uint_as_float(u & 0xFFFF0000u);
    s0 += lo; s1 += hi;
    q0 = fmaf(lo,lo,q0); q1 = fmaf(hi,hi,q1);
  }
  l0[t]=s0; l1[t]=s1; l2[t]=q0; l3[t]=q1;
  __syncthreads();
  if(t<64){
    s0 = l0[t]+l0[t+64]+l0[t+128]+l0[t+192];
    s1 = l1[t]+l1[t+64]+l1[t+128]+l1[t+192];
    q0 = l2[t]+l2[t+64]+l2[t+128]+l2[t+192];
    q1 = l3[t]+l3[t+64]+l3[t+128]+l3[t+192];
    atomicAdd(&sums[2*t],   s0); atomicAdd(&sums[2*t+1],   s1);
    atomicAdd(&sums[128+2*t], q0); atomicAdd(&sums[128+2*t+1], q1);
  }
}

// finalize BN scale/shift; self-clears sums for the next layer
__global__ void k_bnfin(float* __restrict__ sums, const float* __restrict__ g,
                        const float* __restrict__ be, float* __restrict__ ss){
  int c = threadIdx.x;
  if(c<128){
    float inv = 1.f/(float)NN;
    float mu = sums[c]*inv;
    float var = sums[128+c]*inv - mu*mu;
    float sc = g[c]*rsqrtf(var + 1e-5f);
    ss[c] = sc;
    ss[128+c] = fmaf(-sc, mu, be[c]);
    sums[c] = 0.f;
    sums[128+c] = 0.f;
  }
}

// ---------- edge head over dst-CSR-ordered edges ----------
__global__ __launch_bounds__(256) void k_edge(const int* __restrict__ csr_src,
    const int* __restrict__ csr_dst, const int* __restrict__ csr_eid,
    const unsigned short* __restrict__ P16, const unsigned short* __restrict__ Q16,
    const unsigned short* __restrict__ wc2t, const float* __restrict__ bc2,
    const float* __restrict__ wc3, const float* __restrict__ bc3,
    float* __restrict__ out){
  __shared__ char sZ1[64*256];    // z1 bf16 [64 edges][128], swizzled
  __shared__ char sW[64*256];     // Wc2^T bf16 [64 cols][128 k], swizzled
  __shared__ float sWc3[128];
  __shared__ int sSrc[64], sDst[64], sEid[64];
  int t = threadIdx.x;
  int base = blockIdx.x*64;
  if(t<64) sSrc[t] = csr_src[base+t];
  else if(t<128) sDst[t-64] = csr_dst[base+t-64];
  else if(t<192) sEid[t-128] = csr_eid[base+t-128];
  if(t<128) sWc3[t] = wc3[t];
  {
    const uint4* gw = (const uint4*)wc2t;
    #pragma unroll
    for(int i=0;i<4;i++){
      int G = t*4+i;
      int byte = G*16;
      *(uint4*)(sW + SWZ(byte)) = gw[G];
    }
  }
  __syncthreads();
  {
    int r = t>>2, ch = t&3;
    const uint4* prow = (const uint4*)(P16 + (size_t)sSrc[r]*D + ch*32);
    const uint4* qrow = (const uint4*)(Q16 + (size_t)sDst[r]*D + ch*32);
    #pragma unroll
    for(int g=0; g<4; g++){
      uint4 pv = prow[g], qv = qrow[g];
      unsigned int* pp=(unsigned int*)&pv;
      unsigned int* qq=(unsigned int*)&qv;
      uint4 ov; unsigned int* oo=(unsigned int*)&ov;
      #pragma unroll
      for(int j=0;j<4;j++){
        float plo = bf2f(pp[j] & 0xFFFFu);
        float phi = __uint_as_float(pp[j] & 0xFFFF0000u);
        float qlo = bf2f(qq[j] & 0xFFFFu);
        float qhi = __uint_as_float(qq[j] & 0xFFFF0000u);
        float lo = fmaxf(plo+qlo, 0.f);
        float hi = fmaxf(phi+qhi, 0.f);
        oo[j] = f2bf(lo) | (f2bf(hi)<<16);
      }
      int byte = r*256 + ch*64 + g*16;
      *(uint4*)(sZ1 + SWZ(byte)) = ov;
    }
  }
  __syncthreads();
  int w = t>>6, l = t&63;
  int lr = l&15, lk = l>>4;
  f32x4 acc[4] = {{0.f,0.f,0.f,0.f},{0.f,0.f,0.f,0.f},{0.f,0.f,0.f,0.f},{0.f,0.f,0.f,0.f}};
  #pragma unroll
  for(int kk=0; kk<4; kk++){
    int abyte = (16*w + lr)*256 + kk*64 + lk*16;
    short8 a = *(const short8*)(sZ1 + SWZ(abyte));
    #pragma unroll
    for(int n=0;n<4;n++){
      int bbyte = (16*n + lr)*256 + kk*64 + lk*16;
      short8 bf = *(const short8*)(sW + SWZ(bbyte));
      acc[n] = __builtin_amdgcn_mfma_f32_16x16x32_bf16(a, bf, acc[n], 0, 0, 0);
    }
  }
  float w30[4], w31[4], bb2[4];
  #pragma unroll
  for(int n=0;n<4;n++){
    int col = 16*n + lr;
    w30[n] = sWc3[col*2+0];
    w31[n] = sWc3[col*2+1];
    bb2[n] = bc2[col];
  }
  float c30 = bc3[0], c31 = bc3[1];
  #pragma unroll
  for(int reg=0; reg<4; reg++){
    float s0=0.f, s1=0.f;
    #pragma unroll
    for(int n=0;n<4;n++){
      float z = fmaxf(acc[n][reg] + bb2[n], 0.f);
      s0 = fmaf(z, w30[n], s0);
      s1 = fmaf(z, w31[n], s1);
    }
    #pragma unroll
    for(int off=1; off<16; off<<=1){
      s0 += __shfl_xor(s0, off, 64);
      s1 += __shfl_xor(s1, off, 64);
    }
    if(lr==0){
      int eid = sEid[16*w + lk*4 + reg];
      float2 res; res.x = s0 + c30; res.y = s1 + c31;
      *(float2*)(out + (size_t)eid*2) = res;
    }
  }
}

extern "C" void kernel_launch(void* const* d_in, const int* in_sizes, int n_in,
                              void* d_out, int out_size, void* d_ws, size_t ws_size,
                              hipStream_t stream) {
  const float* x   = (const float*)d_in[0];
  const int* ei    = (const int*)d_in[1];
  const int* src0  = ei;
  const int* dst0  = ei + NE;
  const float* W1  = (const float*)d_in[2];
  const float* W2  = (const float*)d_in[4];
  const float* W3  = (const float*)d_in[6];
  const float* g1  = (const float*)d_in[8];
  const float* be1 = (const float*)d_in[9];
  const float* g2  = (const float*)d_in[10];
  const float* be2 = (const float*)d_in[11];
  const float* g3  = (const float*)d_in[12];
  const float* be3 = (const float*)d_in[13];
  const float* Wc1 = (const float*)d_in[14];
  const float* bc1 = (const float*)d_in[15];
  const float* Wc2 = (const float*)d_in[16];
  const float* bc2 = (const float*)d_in[17];
  const float* Wc3 = (const float*)d_in[18];
  const float* bc3 = (const float*)d_in[19];
  float* out = (float*)d_out;

  char* ws = (char*)d_ws;
  size_t off = 0;
  auto alloc = [&](size_t bytes) -> void* {
    void* p = ws + off;
    off += (bytes + 511) & ~(size_t)511;
    return p;
  };
  int*   rowptr  = (int*)alloc((NN+1)*sizeof(int));
  int*   cnt     = (int*)alloc(NN*sizeof(int));
  int*   bsum    = (int*)alloc(256*sizeof(int));
  int*   boff    = (int*)alloc(256*sizeof(int));
  int*   csr_src = (int*)alloc(NE*sizeof(int));
  int*   csr_dst = (int*)alloc(NE*sizeof(int));
  int*   csr_eid = (int*)alloc(NE*sizeof(int));
  float* dinv    = (float*)alloc(NN*sizeof(float));
  unsigned short* U16 = (unsigned short*)alloc((size_t)NN*D*2);  // also P
  unsigned short* H16 = (unsigned short*)alloc((size_t)NN*D*2);
  unsigned short* Q16 = (unsigned short*)alloc((size_t)NN*D*2);
  float* sums    = (float*)alloc(256*sizeof(float));
  float* ss      = (float*)alloc(256*sizeof(float));
  unsigned short* w1T  = (unsigned short*)alloc(128*128*2);
  unsigned short* w2T  = (unsigned short*)alloc(128*128*2);
  unsigned short* w3T  = (unsigned short*)alloc(128*128*2);
  unsigned short* wc1aT= (unsigned short*)alloc(128*128*2);
  unsigned short* wc1bT= (unsigned short*)alloc(128*128*2);
  unsigned short* wc2T = (unsigned short*)alloc(64*128*2);

  const int NB = (NN + 255)/256;   // 196

  // CSR by dst + degrees (hierarchical scan)
  hipMemsetAsync(cnt, 0, NN*sizeof(int), stream);
  hipMemsetAsync(sums, 0, 256*sizeof(float), stream);
  k_hist<<<NE/256, 256, 0, stream>>>(dst0, cnt);
  k_scanA<<<NB, 256, 0, stream>>>(cnt, bsum);
  k_scanB<<<1, 256, 0, stream>>>(bsum, boff, NB);
  k_scanC<<<NB, 256, 0, stream>>>(cnt, boff, rowptr, dinv, cnt);
  k_fill<<<NE/256, 256, 0, stream>>>(src0, dst0, rowptr, cnt, csr_src, csr_dst, csr_eid);
  k_prep_all<<<352, 256, 0, stream>>>(W1, W2, W3, Wc1, Wc2, w1T, w2T, w3T, wc1aT, wc1bT, wc2T);

  const int MMB = (NN + 63)/64;    // 782
  const int GB  = (NN + 3)/4;      // 12500

  // layer 1 (fp32 input converted in-kernel)
  k_mm<<<MMB, 256, 0, stream>>>(nullptr, x, w1T, U16, nullptr, dinv, nullptr);
  k_gather16<<<GB, 256, 0, stream>>>(U16, rowptr, csr_src, dinv, H16);
  k_bnstats16<<<256, 256, 0, stream>>>(H16, sums);
  k_bnfin<<<1, 128, 0, stream>>>(sums, g1, be1, ss);
  // layer 2
  k_mm<<<MMB, 256, 0, stream>>>(H16, nullptr, w2T, U16, ss, dinv, nullptr);
  k_gather16<<<GB, 256, 0, stream>>>(U16, rowptr, csr_src, dinv, H16);
  k_bnstats16<<<256, 256, 0, stream>>>(H16, sums);
  k_bnfin<<<1, 128, 0, stream>>>(sums, g2, be2, ss);
  // layer 3
  k_mm<<<MMB, 256, 0, stream>>>(H16, nullptr, w3T, U16, ss, dinv, nullptr);
  k_gather16<<<GB, 256, 0, stream>>>(U16, rowptr, csr_src, dinv, H16);
  k_bnstats16<<<256, 256, 0, stream>>>(H16, sums);
  k_bnfin<<<1, 128, 0, stream>>>(sums, g3, be3, ss);

  // head projections: P = bnrelu(H)@Wc1_top + bc1 ; Q = bnrelu(H)@Wc1_bot
  k_mm<<<MMB, 256, 0, stream>>>(H16, nullptr, wc1aT, U16, ss, nullptr, bc1);
  k_mm<<<MMB, 256, 0, stream>>>(H16, nullptr, wc1bT, Q16, ss, nullptr, nullptr);

  // edge MLP over CSR-ordered edges
  k_edge<<<NE/64, 256, 0, stream>>>(csr_src, csr_dst, csr_eid, U16, Q16, wc2T,
                                    bc2, Wc3, bc3, out);
}